// Round 1
// baseline (12812.570 us; speedup 1.0000x reference)
//
#include <hip/hip_runtime.h>
#include <math.h>

#define TTOK 8192   // B*S
#define DIMD 512
#define NHEAD 8
#define DHEAD 64
#define SEQ 2048
#define NEXP 8
#define NFF 2048
#define NLAYER 4

#define BM 128
#define BN 64
#define BK 32

// ---------------- embedding + positional encoding ----------------
__global__ __launch_bounds__(256) void embed_kernel(
    const int* __restrict__ tokens, const float* __restrict__ emb,
    float* __restrict__ x) {
  int idx = blockIdx.x * 256 + threadIdx.x;        // over TTOK*DIMD
  int t = idx >> 9;
  int d = idx & 511;
  int s = t & (SEQ - 1);
  int tok = tokens[t];
  float j2 = (float)((d >> 1) << 1);
  // 10000^(-j2/512) = exp(-j2 * ln(10000)/512)
  float freq = expf(-j2 * (9.210340371976184f / 512.0f));
  float angle = (float)s * freq;
  float pe = (d & 1) ? cosf(angle) : sinf(angle);
  x[idx] = emb[tok * DIMD + d] * 22.627416997969522f + pe;
}

// ---------------- generic fp32 GEMM: C = A[M,K] @ B[K,N] + bias ----------------
__global__ __launch_bounds__(256) void gemm_bias_kernel(
    const float* __restrict__ A, const float* __restrict__ B,
    const float* __restrict__ bias, float* __restrict__ C,
    int M, int N, int K) {
  __shared__ float AsT[BK][BM + 4];
  __shared__ float Bs[BK][BN];
  int t = threadIdx.x;
  int m0 = blockIdx.x * BM;
  int n0 = blockIdx.y * BN;
  int tx = t & 15;
  int ty = t >> 4;
  float acc[8][4];
#pragma unroll
  for (int i = 0; i < 8; i++)
#pragma unroll
    for (int j = 0; j < 4; j++) acc[i][j] = 0.0f;

  for (int kt = 0; kt < K; kt += BK) {
#pragma unroll
    for (int i = 0; i < 4; i++) {
      int idx4 = t + i * 256;
      int m = idx4 >> 3;
      int k0 = (idx4 & 7) << 2;
      float4 av = *(const float4*)(A + (size_t)(m0 + m) * K + kt + k0);
      AsT[k0 + 0][m] = av.x; AsT[k0 + 1][m] = av.y;
      AsT[k0 + 2][m] = av.z; AsT[k0 + 3][m] = av.w;
    }
#pragma unroll
    for (int i = 0; i < 2; i++) {
      int idx4 = t + i * 256;
      int r = idx4 >> 4;
      int c4 = idx4 & 15;
      *(float4*)(&Bs[r][c4 << 2]) =
          *(const float4*)(B + (size_t)(kt + r) * N + n0 + (c4 << 2));
    }
    __syncthreads();
#pragma unroll
    for (int kk = 0; kk < BK; kk++) {
      float4 b4 = *(const float4*)(&Bs[kk][tx << 2]);
      float4 a0 = *(const float4*)(&AsT[kk][ty << 3]);
      float4 a1 = *(const float4*)(&AsT[kk][(ty << 3) + 4]);
      float a[8] = {a0.x, a0.y, a0.z, a0.w, a1.x, a1.y, a1.z, a1.w};
      float b[4] = {b4.x, b4.y, b4.z, b4.w};
#pragma unroll
      for (int i = 0; i < 8; i++)
#pragma unroll
        for (int j = 0; j < 4; j++) acc[i][j] += a[i] * b[j];
    }
    __syncthreads();
  }
  float4 bv = *(const float4*)(bias + n0 + (tx << 2));
#pragma unroll
  for (int i = 0; i < 8; i++) {
    float4 o;
    o.x = acc[i][0] + bv.x; o.y = acc[i][1] + bv.y;
    o.z = acc[i][2] + bv.z; o.w = acc[i][3] + bv.w;
    *(float4*)(C + (size_t)(m0 + (ty << 3) + i) * N + n0 + (tx << 2)) = o;
  }
}

// ---------------- flash-style attention (fp32, online softmax) ----------------
// q,k,v,out: [T, 512] with head h at cols h*64..h*64+63
__global__ __launch_bounds__(256) void attn_kernel(
    const float* __restrict__ q, const float* __restrict__ k,
    const float* __restrict__ v, float* __restrict__ out) {
  __shared__ float Ks[64][64];
  __shared__ float Vs[64][64];
  int t = threadIdx.x;
  int part = t & 3;     // 4 lanes per query (adjacent in wave)
  int qr = t >> 2;      // query within tile, 0..63
  int qtile = blockIdx.x;
  int bh = blockIdx.y;
  int b = bh >> 3, h = bh & 7;
  const float* qbase = q + (size_t)b * SEQ * DIMD + h * DHEAD;
  const float* kbase = k + (size_t)b * SEQ * DIMD + h * DHEAD;
  const float* vbase = v + (size_t)b * SEQ * DIMD + h * DHEAD;
  float* obase = out + (size_t)b * SEQ * DIMD + h * DHEAD;
  int qrow = qtile * 64 + qr;

  float qreg[16];
#pragma unroll
  for (int j = 0; j < 16; j += 4) {
    float4 tmp = *(const float4*)(qbase + (size_t)qrow * DIMD + part * 16 + j);
    qreg[j] = tmp.x; qreg[j + 1] = tmp.y; qreg[j + 2] = tmp.z; qreg[j + 3] = tmp.w;
  }
  float m = -1e30f, l = 0.0f;
  float O[16];
#pragma unroll
  for (int j = 0; j < 16; j++) O[j] = 0.0f;

  for (int kt = 0; kt < SEQ / 64; kt++) {
#pragma unroll
    for (int i = 0; i < 4; i++) {
      int idx4 = t + i * 256;
      int r = idx4 >> 4;
      int c4 = idx4 & 15;
      *(float4*)(&Ks[r][c4 << 2]) =
          *(const float4*)(kbase + (size_t)(kt * 64 + r) * DIMD + (c4 << 2));
      *(float4*)(&Vs[r][c4 << 2]) =
          *(const float4*)(vbase + (size_t)(kt * 64 + r) * DIMD + (c4 << 2));
    }
    __syncthreads();
    for (int kk = 0; kk < 64; kk++) {
      float p = 0.0f;
#pragma unroll
      for (int j = 0; j < 16; j++) p += qreg[j] * Ks[kk][part * 16 + j];
      p += __shfl_xor(p, 1);
      p += __shfl_xor(p, 2);
      float s = p * 0.125f;  // 1/sqrt(64)
      float mnew = fmaxf(m, s);
      float alpha = __expf(m - mnew);
      float pr = __expf(s - mnew);
      l = l * alpha + pr;
#pragma unroll
      for (int j = 0; j < 16; j++)
        O[j] = O[j] * alpha + pr * Vs[kk][part * 16 + j];
      m = mnew;
    }
    __syncthreads();
  }
  float inv = 1.0f / l;
#pragma unroll
  for (int j = 0; j < 16; j += 4) {
    float4 o4;
    o4.x = O[j] * inv; o4.y = O[j + 1] * inv;
    o4.z = O[j + 2] * inv; o4.w = O[j + 3] * inv;
    *(float4*)(obase + (size_t)qrow * DIMD + part * 16 + j) = o4;
  }
}

// ---------------- LayerNorm(x + p) * g + be ----------------
__global__ __launch_bounds__(256) void ln_add_kernel(
    const float* __restrict__ x, const float* __restrict__ p,
    const float* __restrict__ g, const float* __restrict__ be,
    float* __restrict__ out) {
  int wave = threadIdx.x >> 6;
  int lane = threadIdx.x & 63;
  int token = blockIdx.x * 4 + wave;
  const float* xr = x + (size_t)token * DIMD;
  const float* pr = p + (size_t)token * DIMD;
  float vals[8];
  float sum = 0.0f;
#pragma unroll
  for (int j = 0; j < 8; j += 4) {
    float4 a = *(const float4*)(xr + lane * 8 + j);
    float4 b = *(const float4*)(pr + lane * 8 + j);
    vals[j] = a.x + b.x; vals[j + 1] = a.y + b.y;
    vals[j + 2] = a.z + b.z; vals[j + 3] = a.w + b.w;
    sum += vals[j] + vals[j + 1] + vals[j + 2] + vals[j + 3];
  }
#pragma unroll
  for (int off = 32; off; off >>= 1) sum += __shfl_xor(sum, off);
  float mu = sum * (1.0f / 512.0f);
  float sq = 0.0f;
#pragma unroll
  for (int j = 0; j < 8; j++) { vals[j] -= mu; sq += vals[j] * vals[j]; }
#pragma unroll
  for (int off = 32; off; off >>= 1) sq += __shfl_xor(sq, off);
  float rs = rsqrtf(sq * (1.0f / 512.0f) + 1e-6f);
#pragma unroll
  for (int j = 0; j < 8; j++) {
    int d = lane * 8 + j;
    out[(size_t)token * DIMD + d] = vals[j] * rs * g[d] + be[d];
  }
}

// ---------------- LayerNorm(out1 + g0*o0 + g1*o1) * g + be ----------------
__global__ __launch_bounds__(256) void ln_moe_kernel(
    const float* __restrict__ out1, const float* __restrict__ oslot,
    const float* __restrict__ gates, const float* __restrict__ g,
    const float* __restrict__ be, float* __restrict__ out) {
  int wave = threadIdx.x >> 6;
  int lane = threadIdx.x & 63;
  int token = blockIdx.x * 4 + wave;
  const float* xr = out1 + (size_t)token * DIMD;
  const float* o0 = oslot + (size_t)(token * 2) * DIMD;
  const float* o1 = oslot + (size_t)(token * 2 + 1) * DIMD;
  float g0 = gates[token * 2], g1 = gates[token * 2 + 1];
  float vals[8];
  float sum = 0.0f;
#pragma unroll
  for (int j = 0; j < 8; j += 4) {
    float4 a = *(const float4*)(xr + lane * 8 + j);
    float4 b = *(const float4*)(o0 + lane * 8 + j);
    float4 c = *(const float4*)(o1 + lane * 8 + j);
    vals[j]     = a.x + g0 * b.x + g1 * c.x;
    vals[j + 1] = a.y + g0 * b.y + g1 * c.y;
    vals[j + 2] = a.z + g0 * b.z + g1 * c.z;
    vals[j + 3] = a.w + g0 * b.w + g1 * c.w;
    sum += vals[j] + vals[j + 1] + vals[j + 2] + vals[j + 3];
  }
#pragma unroll
  for (int off = 32; off; off >>= 1) sum += __shfl_xor(sum, off);
  float mu = sum * (1.0f / 512.0f);
  float sq = 0.0f;
#pragma unroll
  for (int j = 0; j < 8; j++) { vals[j] -= mu; sq += vals[j] * vals[j]; }
#pragma unroll
  for (int off = 32; off; off >>= 1) sq += __shfl_xor(sq, off);
  float rs = rsqrtf(sq * (1.0f / 512.0f) + 1e-6f);
#pragma unroll
  for (int j = 0; j < 8; j++) {
    int d = lane * 8 + j;
    out[(size_t)token * DIMD + d] = vals[j] * rs * g[d] + be[d];
  }
}

// ---------------- MoE routing: softmax top-2 + bucket by expert ----------------
__global__ __launch_bounds__(256) void route_kernel(
    const float* __restrict__ x, const float* __restrict__ Wg,
    const float* __restrict__ bg, float* __restrict__ gates,
    int* __restrict__ lists, int* __restrict__ counts) {
  int wave = threadIdx.x >> 6;
  int lane = threadIdx.x & 63;
  int token = blockIdx.x * 4 + wave;
  const float* xr = x + (size_t)token * DIMD;
  float acc[8];
#pragma unroll
  for (int e = 0; e < 8; e++) acc[e] = 0.0f;
  for (int it = 0; it < 8; it++) {
    int d = it * 64 + lane;
    float xv = xr[d];
    float4 w0 = *(const float4*)(Wg + d * 8);
    float4 w1 = *(const float4*)(Wg + d * 8 + 4);
    acc[0] += xv * w0.x; acc[1] += xv * w0.y;
    acc[2] += xv * w0.z; acc[3] += xv * w0.w;
    acc[4] += xv * w1.x; acc[5] += xv * w1.y;
    acc[6] += xv * w1.z; acc[7] += xv * w1.w;
  }
#pragma unroll
  for (int e = 0; e < 8; e++)
#pragma unroll
    for (int off = 32; off; off >>= 1) acc[e] += __shfl_xor(acc[e], off);
  if (lane == 0) {
    float lg[8];
    float mx = -1e30f;
#pragma unroll
    for (int e = 0; e < 8; e++) { lg[e] = acc[e] + bg[e]; mx = fmaxf(mx, lg[e]); }
#pragma unroll
    for (int e = 0; e < 8; e++) lg[e] = __expf(lg[e] - mx);
    int i0 = 0; float v0 = lg[0];
#pragma unroll
    for (int e = 1; e < 8; e++) if (lg[e] > v0) { v0 = lg[e]; i0 = e; }
    int i1 = -1; float v1 = -1.0f;
#pragma unroll
    for (int e = 0; e < 8; e++)
      if (e != i0 && lg[e] > v1) { v1 = lg[e]; i1 = e; }
    // gates normalized over top-2: softmax denominator cancels
    float inv = 1.0f / (v0 + v1);
    gates[token * 2] = v0 * inv;
    gates[token * 2 + 1] = v1 * inv;
    int p0 = atomicAdd(&counts[i0], 1);
    lists[i0 * TTOK + p0] = token * 2;
    int p1 = atomicAdd(&counts[i1], 1);
    lists[i1 * TTOK + p1] = token * 2 + 1;
  }
}

__global__ void zero_counts_kernel(int* counts) {
  if (threadIdx.x < NEXP) counts[threadIdx.x] = 0;
}

// ---------------- FFN1: h[enc] = relu(out1[token] @ W1[e][:,chunk] + b1) ----------------
__global__ __launch_bounds__(256) void ffn1_kernel(
    const float* __restrict__ X, const float* __restrict__ W1,
    const float* __restrict__ b1, float* __restrict__ Hbuf,
    const int* __restrict__ lists, const int* __restrict__ counts,
    int fchunk) {
  int e = blockIdx.z;
  int cnt = counts[e];
  int m0 = blockIdx.x * BM;
  if (m0 >= cnt) return;
  int n0 = blockIdx.y * BN;
  const float* B = W1 + (size_t)e * DIMD * NFF + fchunk * 512;  // ldb = NFF
  const float* bias = b1 + (size_t)e * NFF + fchunk * 512;
  const int* list = lists + e * TTOK;

  __shared__ float AsT[BK][BM + 4];
  __shared__ float Bs[BK][BN];
  __shared__ int rowenc[BM];
  int t = threadIdx.x;
  if (t < BM) {
    int r = m0 + t;
    rowenc[t] = (r < cnt) ? list[r] : -1;
  }
  __syncthreads();
  int tx = t & 15;
  int ty = t >> 4;
  float acc[8][4];
#pragma unroll
  for (int i = 0; i < 8; i++)
#pragma unroll
    for (int j = 0; j < 4; j++) acc[i][j] = 0.0f;

  for (int kt = 0; kt < DIMD; kt += BK) {
#pragma unroll
    for (int i = 0; i < 4; i++) {
      int idx4 = t + i * 256;
      int m = idx4 >> 3;
      int k0 = (idx4 & 7) << 2;
      int enc = rowenc[m];
      float4 av = make_float4(0.f, 0.f, 0.f, 0.f);
      if (enc >= 0)
        av = *(const float4*)(X + (size_t)(enc >> 1) * DIMD + kt + k0);
      AsT[k0 + 0][m] = av.x; AsT[k0 + 1][m] = av.y;
      AsT[k0 + 2][m] = av.z; AsT[k0 + 3][m] = av.w;
    }
#pragma unroll
    for (int i = 0; i < 2; i++) {
      int idx4 = t + i * 256;
      int r = idx4 >> 4;
      int c4 = idx4 & 15;
      *(float4*)(&Bs[r][c4 << 2]) =
          *(const float4*)(B + (size_t)(kt + r) * NFF + n0 + (c4 << 2));
    }
    __syncthreads();
#pragma unroll
    for (int kk = 0; kk < BK; kk++) {
      float4 b4 = *(const float4*)(&Bs[kk][tx << 2]);
      float4 a0 = *(const float4*)(&AsT[kk][ty << 3]);
      float4 a1 = *(const float4*)(&AsT[kk][(ty << 3) + 4]);
      float a[8] = {a0.x, a0.y, a0.z, a0.w, a1.x, a1.y, a1.z, a1.w};
      float b[4] = {b4.x, b4.y, b4.z, b4.w};
#pragma unroll
      for (int i = 0; i < 8; i++)
#pragma unroll
        for (int j = 0; j < 4; j++) acc[i][j] += a[i] * b[j];
    }
    __syncthreads();
  }
  float4 bv = *(const float4*)(bias + n0 + (tx << 2));
#pragma unroll
  for (int i = 0; i < 8; i++) {
    int enc = rowenc[(ty << 3) + i];
    if (enc >= 0) {
      float4 o;
      o.x = fmaxf(acc[i][0] + bv.x, 0.f);
      o.y = fmaxf(acc[i][1] + bv.y, 0.f);
      o.z = fmaxf(acc[i][2] + bv.z, 0.f);
      o.w = fmaxf(acc[i][3] + bv.w, 0.f);
      *(float4*)(Hbuf + (size_t)enc * 512 + n0 + (tx << 2)) = o;
    }
  }
}

// ---------------- FFN2: oslot[enc] (c==0? = : +=) h[enc] @ W2[e][chunk,:] (+b2 at c0) ----------------
__global__ __launch_bounds__(256) void ffn2_kernel(
    const float* __restrict__ Hbuf, const float* __restrict__ W2,
    const float* __restrict__ b2, float* __restrict__ Oslot,
    const int* __restrict__ lists, const int* __restrict__ counts,
    int fchunk) {
  int e = blockIdx.z;
  int cnt = counts[e];
  int m0 = blockIdx.x * BM;
  if (m0 >= cnt) return;
  int n0 = blockIdx.y * BN;
  const float* B = W2 + (size_t)e * NFF * DIMD + (size_t)(fchunk * 512) * DIMD;  // ldb = DIMD
  const float* bias = b2 + (size_t)e * DIMD;
  const int* list = lists + e * TTOK;

  __shared__ float AsT[BK][BM + 4];
  __shared__ float Bs[BK][BN];
  __shared__ int rowenc[BM];
  int t = threadIdx.x;
  if (t < BM) {
    int r = m0 + t;
    rowenc[t] = (r < cnt) ? list[r] : -1;
  }
  __syncthreads();
  int tx = t & 15;
  int ty = t >> 4;
  float acc[8][4];
#pragma unroll
  for (int i = 0; i < 8; i++)
#pragma unroll
    for (int j = 0; j < 4; j++) acc[i][j] = 0.0f;

  for (int kt = 0; kt < 512; kt += BK) {
#pragma unroll
    for (int i = 0; i < 4; i++) {
      int idx4 = t + i * 256;
      int m = idx4 >> 3;
      int k0 = (idx4 & 7) << 2;
      int enc = rowenc[m];
      float4 av = make_float4(0.f, 0.f, 0.f, 0.f);
      if (enc >= 0)
        av = *(const float4*)(Hbuf + (size_t)enc * 512 + kt + k0);
      AsT[k0 + 0][m] = av.x; AsT[k0 + 1][m] = av.y;
      AsT[k0 + 2][m] = av.z; AsT[k0 + 3][m] = av.w;
    }
#pragma unroll
    for (int i = 0; i < 2; i++) {
      int idx4 = t + i * 256;
      int r = idx4 >> 4;
      int c4 = idx4 & 15;
      *(float4*)(&Bs[r][c4 << 2]) =
          *(const float4*)(B + (size_t)(kt + r) * DIMD + n0 + (c4 << 2));
    }
    __syncthreads();
#pragma unroll
    for (int kk = 0; kk < BK; kk++) {
      float4 b4 = *(const float4*)(&Bs[kk][tx << 2]);
      float4 a0 = *(const float4*)(&AsT[kk][ty << 3]);
      float4 a1 = *(const float4*)(&AsT[kk][(ty << 3) + 4]);
      float a[8] = {a0.x, a0.y, a0.z, a0.w, a1.x, a1.y, a1.z, a1.w};
      float b[4] = {b4.x, b4.y, b4.z, b4.w};
#pragma unroll
      for (int i = 0; i < 8; i++)
#pragma unroll
        for (int j = 0; j < 4; j++) acc[i][j] += a[i] * b[j];
    }
    __syncthreads();
  }
  float4 bv = *(const float4*)(bias + n0 + (tx << 2));
#pragma unroll
  for (int i = 0; i < 8; i++) {
    int enc = rowenc[(ty << 3) + i];
    if (enc >= 0) {
      float* dst = Oslot + (size_t)enc * DIMD + n0 + (tx << 2);
      float4 o;
      if (fchunk == 0) {
        o.x = acc[i][0] + bv.x; o.y = acc[i][1] + bv.y;
        o.z = acc[i][2] + bv.z; o.w = acc[i][3] + bv.w;
      } else {
        float4 old = *(const float4*)dst;
        o.x = old.x + acc[i][0]; o.y = old.y + acc[i][1];
        o.z = old.z + acc[i][2]; o.w = old.w + acc[i][3];
      }
      *(float4*)dst = o;
    }
  }
}

// ---------------- host orchestration ----------------
extern "C" void kernel_launch(void* const* d_in, const int* in_sizes, int n_in,
                              void* d_out, int out_size, void* d_ws, size_t ws_size,
                              hipStream_t stream) {
  (void)in_sizes; (void)n_in; (void)out_size; (void)ws_size;
  const int*   tokens = (const int*)d_in[0];
  const float* emb = (const float*)d_in[1];
  const float* Wq = (const float*)d_in[2];
  const float* bq = (const float*)d_in[3];
  const float* Wk = (const float*)d_in[4];
  const float* bk = (const float*)d_in[5];
  const float* Wv = (const float*)d_in[6];
  const float* bv = (const float*)d_in[7];
  const float* Wo = (const float*)d_in[8];
  const float* bo = (const float*)d_in[9];
  const float* Wg = (const float*)d_in[10];
  const float* bg = (const float*)d_in[11];
  const float* W1 = (const float*)d_in[12];
  const float* b1 = (const float*)d_in[13];
  const float* W2 = (const float*)d_in[14];
  const float* b2 = (const float*)d_in[15];
  const float* g1 = (const float*)d_in[16];
  const float* be1 = (const float*)d_in[17];
  const float* g2 = (const float*)d_in[18];
  const float* be2 = (const float*)d_in[19];

  const size_t MB4 = 4u * 1024u * 1024u;  // floats per [T,512] buffer
  float* ws = (float*)d_ws;
  float* X    = ws;             // 0..4M
  float* Q    = ws + 4 * MB4 / 4;  // offsets in floats: 4M each
  float* Kb   = ws + 8 * (MB4 / 4);
  float* Vb   = ws + 12 * (MB4 / 4);
  float* ATT  = ws + 16 * (MB4 / 4);
  float* PROJ = ws + 20 * (MB4 / 4);
  float* OUT1 = ws + 24 * (MB4 / 4);
  // reuse: q/k/v/attn dead during MoE
  float* Hbuf  = Q;    // 8M floats (spans Q+Kb)
  float* Oslot = Vb;   // 8M floats (spans Vb+ATT)
  float* GATES = ws + 28 * (MB4 / 4);            // 16384 floats
  int*   LISTS = (int*)(ws + 28 * (MB4 / 4) + 16384);  // 8*8192 ints
  int*   COUNTS = (int*)((float*)LISTS + 65536);       // reuse float slots as ints

  dim3 blk(256);
  embed_kernel<<<(TTOK * DIMD) / 256, blk, 0, stream>>>(tokens, emb, X);

  for (int i = 0; i < NLAYER; i++) {
    const float* wq = Wq + (size_t)i * DIMD * DIMD;
    const float* wk = Wk + (size_t)i * DIMD * DIMD;
    const float* wv = Wv + (size_t)i * DIMD * DIMD;
    const float* wo = Wo + (size_t)i * DIMD * DIMD;
    const float* bqi = bq + (size_t)i * DIMD;
    const float* bki = bk + (size_t)i * DIMD;
    const float* bvi = bv + (size_t)i * DIMD;
    const float* boi = bo + (size_t)i * DIMD;
    const float* wgi = Wg + (size_t)i * DIMD * NEXP;
    const float* bgi = bg + (size_t)i * NEXP;
    const float* w1i = W1 + (size_t)i * NEXP * DIMD * NFF;
    const float* b1i = b1 + (size_t)i * NEXP * NFF;
    const float* w2i = W2 + (size_t)i * NEXP * NFF * DIMD;
    const float* b2i = b2 + (size_t)i * NEXP * DIMD;
    const float* g1i = g1 + (size_t)i * DIMD;
    const float* be1i = be1 + (size_t)i * DIMD;
    const float* g2i = g2 + (size_t)i * DIMD;
    const float* be2i = be2 + (size_t)i * DIMD;

    dim3 gg(TTOK / BM, DIMD / BN);  // (64, 8)
    gemm_bias_kernel<<<gg, blk, 0, stream>>>(X, wq, bqi, Q, TTOK, DIMD, DIMD);
    gemm_bias_kernel<<<gg, blk, 0, stream>>>(X, wk, bki, Kb, TTOK, DIMD, DIMD);
    gemm_bias_kernel<<<gg, blk, 0, stream>>>(X, wv, bvi, Vb, TTOK, DIMD, DIMD);
    attn_kernel<<<dim3(SEQ / 64, 32), blk, 0, stream>>>(Q, Kb, Vb, ATT);
    gemm_bias_kernel<<<gg, blk, 0, stream>>>(ATT, wo, boi, PROJ, TTOK, DIMD, DIMD);
    ln_add_kernel<<<TTOK / 4, blk, 0, stream>>>(X, PROJ, g1i, be1i, OUT1);
    zero_counts_kernel<<<1, 64, 0, stream>>>(COUNTS);
    route_kernel<<<TTOK / 4, blk, 0, stream>>>(OUT1, wgi, bgi, GATES, LISTS, COUNTS);
    for (int c = 0; c < 4; c++) {
      ffn1_kernel<<<dim3(TTOK / BM, 512 / BN, NEXP), blk, 0, stream>>>(
          OUT1, w1i, b1i, Hbuf, LISTS, COUNTS, c);
      ffn2_kernel<<<dim3(TTOK / BM, DIMD / BN, NEXP), blk, 0, stream>>>(
          Hbuf, w2i, b2i, Oslot, LISTS, COUNTS, c);
    }
    float* xout = (i == NLAYER - 1) ? (float*)d_out : X;
    ln_moe_kernel<<<TTOK / 4, blk, 0, stream>>>(OUT1, Oslot, GATES, g2i, be2i, xout);
  }
}